// Round 5
// baseline (426.954 us; speedup 1.0000x reference)
//
#include <hip/hip_runtime.h>

#define B  8
#define NV 4096
#define NE 32768
#define D  128
#define KE2 384   // edge GEMM K after u-fold: De + 2*Dv
#define KN2 256   // node GEMM K after u-fold: Dep + Dv
#define KG 384    // Dep + Dvp + Du

using short8    = __attribute__((ext_vector_type(8))) short;
using f32x4     = __attribute__((ext_vector_type(4))) float;
using ushort4_t = __attribute__((ext_vector_type(4))) unsigned short;

__device__ inline unsigned short f2bf(float f) {
    unsigned u = __builtin_bit_cast(unsigned, f);
    u += 0x7FFFu + ((u >> 16) & 1u);          // RNE
    return (unsigned short)(u >> 16);
}

// swizzled bf16x4 store into LDS tile (XOR bits 4-6 of byte addr with row&7)
__device__ inline void store_bf4(unsigned short* base, int ldus, int row, int j, float4 v) {
    const int byte = (j * 2) ^ ((row & 7) << 4);
    ushort4_t p = { f2bf(v.x), f2bf(v.y), f2bf(v.z), f2bf(v.w) };
    *(ushort4_t*)(base + row * ldus + (byte >> 1)) = p;
}

// ---------------------------------------------------------------------------
// weight prep: WtE[n][k]=bf16(W_edge[k][n]) k<384; WtN[n][k]=bf16(W_node[k][n]) k<256
// ---------------------------------------------------------------------------
__global__ __launch_bounds__(256) void prep_weights(
    const float* __restrict__ We, const float* __restrict__ Wn,
    unsigned short* __restrict__ WtE, unsigned short* __restrict__ WtN)
{
    const int idx = blockIdx.x * 256 + threadIdx.x;       // 0 .. 49151
    {   // edge: 128 x 384
        const int n = idx / KE2, k = idx % KE2;
        WtE[idx] = f2bf(We[(size_t)k * D + n]);
    }
    if (idx < 128 * KN2) {                                 // node: 128 x 256
        const int n = idx >> 8, k = idx & 255;
        WtN[idx] = f2bf(Wn[(size_t)k * D + n]);
    }
}

// ---------------------------------------------------------------------------
// bias fold: bias_e[b][n] = b_e[n] + u[b]@W_e[384:,n] ; bias_n likewise (fp32)
// ---------------------------------------------------------------------------
__global__ __launch_bounds__(128) void bias_kernel(
    const float* __restrict__ gu,
    const float* __restrict__ We, const float* __restrict__ be,
    const float* __restrict__ Wn, const float* __restrict__ bn,
    float* __restrict__ bias_e, float* __restrict__ bias_n)
{
    const int b = blockIdx.x, n = threadIdx.x;
    float se = be[n], sn = bn[n];
    for (int k = 0; k < D; ++k) {
        const float uk = gu[(size_t)b * D + k];
        se += uk * We[(size_t)(KE2 + k) * D + n];
        sn += uk * Wn[(size_t)(KN2 + k) * D + n];
    }
    bias_e[(size_t)b * D + n] = se;
    bias_n[(size_t)b * D + n] = sn;
}

// ---------------------------------------------------------------------------
// CSR build: histogram -> per-batch exclusive scan -> scatter edge ids
// ---------------------------------------------------------------------------
__global__ __launch_bounds__(256) void hist_kernel(
    const int* __restrict__ edge_rs, const int* __restrict__ edge_masks,
    int* __restrict__ cnt)
{
    const int idx = blockIdx.x * 256 + threadIdx.x;       // over B*NE
    if (edge_masks[idx]) {
        const int b = idx >> 15;                          // NE = 2^15
        const int r = edge_rs[2 * idx];                   // receiver
        atomicAdd(cnt + b * NV + r, 1);
    }
}

__global__ __launch_bounds__(1024) void scan_kernel(
    const int* __restrict__ cnt, int* __restrict__ off, int* __restrict__ cur)
{
    const int b = blockIdx.x, t = threadIdx.x;
    __shared__ int part[1024];
    int4 c = *(const int4*)(cnt + b * NV + t * 4);
    const int s0 = c.x, s1 = s0 + c.y, s2 = s1 + c.z, s3 = s2 + c.w;
    part[t] = s3;
    __syncthreads();
    #pragma unroll
    for (int d = 1; d < 1024; d <<= 1) {
        const int v = (t >= d) ? part[t - d] : 0;
        __syncthreads();
        part[t] += v;
        __syncthreads();
    }
    const int base = part[t] - s3;                        // exclusive
    int* o = off + b * (NV + 1) + t * 4;
    o[0] = base; o[1] = base + s0; o[2] = base + s1; o[3] = base + s2;
    int4 cc = { base, base + s0, base + s1, base + s2 };
    *(int4*)(cur + b * NV + t * 4) = cc;
    if (t == 1023) off[b * (NV + 1) + NV] = part[1023];
}

__global__ __launch_bounds__(256) void scatter_kernel(
    const int* __restrict__ edge_rs, const int* __restrict__ edge_masks,
    int* __restrict__ cur, int* __restrict__ elist)
{
    const int idx = blockIdx.x * 256 + threadIdx.x;
    if (edge_masks[idx]) {
        const int b = idx >> 15;
        const int e = idx & (NE - 1);
        const int r = edge_rs[2 * idx];
        const int pos = atomicAdd(cur + b * NV + r, 1);
        elist[b * NE + pos] = e;
    }
}

// ---------------------------------------------------------------------------
// Edge block (MFMA, swapped operands mfma(W,A)): 64 edges/block, 4 waves,
// wave wv -> features [32wv,32wv+32). K=384. W panel half-split in registers.
// Lane holds 4 consecutive features of one edge row -> float4 stores.
// ---------------------------------------------------------------------------
__global__ __launch_bounds__(256, 3) void edge_kernel(
    const float* __restrict__ nodes,
    const float* __restrict__ edges,
    const int*   __restrict__ edge_rs,
    const unsigned short* __restrict__ WtE,   // (128,384) bf16, n-major
    const float* __restrict__ bias_e,         // (B,128) fp32, u-folded
    float* __restrict__ edges_p,
    float* __restrict__ e2u)
{
    __shared__ unsigned short Ash[64 * KE2];  // 48 KB swizzled bf16 concat tile

    const int b   = blockIdx.y;
    const int e0  = blockIdx.x * 64;
    const int tid = threadIdx.x;
    const int tx  = tid & 31;
    const int ty  = tid >> 5;                 // 0..7
    const int j0  = tx * 4;

    const int lane = tid & 63;
    const int wv   = tid >> 6;                // 0..3 -> feature tile base 32*wv
    const int lc   = lane & 15;
    const int lg   = lane >> 4;

    // receiver/sender indices for this thread's 8 rows (issue early)
    int2 rs_[8];
    #pragma unroll
    for (int i = 0; i < 8; ++i)
        rs_[i] = ((const int2*)edge_rs)[(size_t)b * NE + e0 + ty + 8 * i];

    // first half of the wave's W panel (ks 0..5)
    short8 wregA[6][2];
    #pragma unroll
    for (int ks = 0; ks < 6; ++ks)
        #pragma unroll
        for (int nt = 0; nt < 2; ++nt)
            wregA[ks][nt] = *(const short8*)(WtE + (size_t)(wv * 32 + nt * 16 + lc) * KE2
                                                 + ks * 32 + lg * 8);

    // stage concat tile [edge | nodes[recv] | nodes[send]] into LDS
    #pragma unroll
    for (int i = 0; i < 8; ++i) {
        const int    row = ty + 8 * i;
        const size_t eb  = (size_t)b * NE + e0 + row;
        const float4 ev  = *(const float4*)(edges + eb * (size_t)D + j0);
        const float4 rv  = *(const float4*)(nodes + ((size_t)b * NV + rs_[i].x) * D + j0);
        const float4 sv  = *(const float4*)(nodes + ((size_t)b * NV + rs_[i].y) * D + j0);
        store_bf4(Ash, KE2, row,   0 + j0, ev);
        store_bf4(Ash, KE2, row, 128 + j0, rv);
        store_bf4(Ash, KE2, row, 256 + j0, sv);
    }
    __syncthreads();

    // second half of W panel (ks 6..11) — loads hide under half-1 compute
    short8 wregB[6][2];
    #pragma unroll
    for (int ks = 0; ks < 6; ++ks)
        #pragma unroll
        for (int nt = 0; nt < 2; ++nt)
            wregB[ks][nt] = *(const short8*)(WtE + (size_t)(wv * 32 + nt * 16 + lc) * KE2
                                                 + (ks + 6) * 32 + lg * 8);

    f32x4 acc[4][2] = {};
    #pragma unroll
    for (int ks = 0; ks < 6; ++ks) {
        const int kk = ks * 32 + lg * 8;
        #pragma unroll
        for (int mt = 0; mt < 4; ++mt) {
            const int row  = mt * 16 + lc;
            const int byte = (kk * 2) ^ ((row & 7) << 4);
            const short8 afr = *(const short8*)(Ash + row * KE2 + (byte >> 1));
            acc[mt][0] = __builtin_amdgcn_mfma_f32_16x16x32_bf16(wregA[ks][0], afr, acc[mt][0], 0, 0, 0);
            acc[mt][1] = __builtin_amdgcn_mfma_f32_16x16x32_bf16(wregA[ks][1], afr, acc[mt][1], 0, 0, 0);
        }
    }
    #pragma unroll
    for (int ks = 0; ks < 6; ++ks) {
        const int kk = (ks + 6) * 32 + lg * 8;
        #pragma unroll
        for (int mt = 0; mt < 4; ++mt) {
            const int row  = mt * 16 + lc;
            const int byte = (kk * 2) ^ ((row & 7) << 4);
            const short8 afr = *(const short8*)(Ash + row * KE2 + (byte >> 1));
            acc[mt][0] = __builtin_amdgcn_mfma_f32_16x16x32_bf16(wregB[ks][0], afr, acc[mt][0], 0, 0, 0);
            acc[mt][1] = __builtin_amdgcn_mfma_f32_16x16x32_bf16(wregB[ks][1], afr, acc[mt][1], 0, 0, 0);
        }
    }

    // epilogue: lane (lc,lg) holds rows {mt*16+lc}, features f0..f0+3 (float4)
    #pragma unroll
    for (int nt = 0; nt < 2; ++nt) {
        const int f0 = wv * 32 + nt * 16 + lg * 4;
        const float4 bb = *(const float4*)(bias_e + (size_t)b * D + f0);
        float px = 0.f, py = 0.f, pz = 0.f, pw = 0.f;
        #pragma unroll
        for (int mt = 0; mt < 4; ++mt) {
            const int row = mt * 16 + lc;
            float4 o;
            o.x = fmaxf(acc[mt][nt][0] + bb.x, 0.f);
            o.y = fmaxf(acc[mt][nt][1] + bb.y, 0.f);
            o.z = fmaxf(acc[mt][nt][2] + bb.z, 0.f);
            o.w = fmaxf(acc[mt][nt][3] + bb.w, 0.f);
            *(float4*)(edges_p + ((size_t)b * NE + e0 + row) * D + f0) = o;
            px += o.x; py += o.y; pz += o.z; pw += o.w;
        }
        #pragma unroll
        for (int m = 1; m < 16; m <<= 1) {     // reduce over lc (lane bits 0..3)
            px += __shfl_xor(px, m);
            py += __shfl_xor(py, m);
            pz += __shfl_xor(pz, m);
            pw += __shfl_xor(pw, m);
        }
        if (lc == 0) {
            float* dst = e2u + (size_t)b * D + f0;
            atomicAdd(dst + 0, px);
            atomicAdd(dst + 1, py);
            atomicAdd(dst + 2, pz);
            atomicAdd(dst + 3, pw);
        }
    }
}

// ---------------------------------------------------------------------------
// Node block (MFMA, swapped operands): 64 nodes/block, K=256, CSR gather.
// ---------------------------------------------------------------------------
__global__ __launch_bounds__(256, 3) void node_kernel(
    const float* __restrict__ nodes,
    const float* __restrict__ edges_p,
    const int*   __restrict__ off,            // (B, NV+1)
    const int*   __restrict__ elist,          // (B, NE)
    const unsigned short* __restrict__ WtN,   // (128,256) bf16, n-major
    const float* __restrict__ bias_n,         // (B,128) fp32, u-folded
    float* __restrict__ nodes_p,
    float* __restrict__ v2u)
{
    __shared__ unsigned short Ash[64 * KN2];  // 32 KB

    const int b   = blockIdx.y;
    const int n0  = blockIdx.x * 64;
    const int tid = threadIdx.x;
    const int tx  = tid & 31;
    const int ty  = tid >> 5;
    const int j0  = tx * 4;

    const int lane = tid & 63;
    const int wv   = tid >> 6;
    const int lc   = lane & 15;
    const int lg   = lane >> 4;

    short8 wregA[4][2];
    #pragma unroll
    for (int ks = 0; ks < 4; ++ks)
        #pragma unroll
        for (int nt = 0; nt < 2; ++nt)
            wregA[ks][nt] = *(const short8*)(WtN + (size_t)(wv * 32 + nt * 16 + lc) * KN2
                                                 + ks * 32 + lg * 8);

    #pragma unroll
    for (int i = 0; i < 8; ++i) {
        const int row = ty + 8 * i;
        const int v   = n0 + row;
        const int p0  = off[b * (NV + 1) + v];
        const int p1  = off[b * (NV + 1) + v + 1];
        float ax = 0.f, ay = 0.f, az = 0.f, aw = 0.f;
        for (int p = p0; p < p1; ++p) {
            const int e = elist[b * NE + p];
            const float4 x = *(const float4*)(edges_p + ((size_t)b * NE + e) * D + j0);
            ax += x.x; ay += x.y; az += x.z; aw += x.w;
        }
        const size_t nb = (size_t)b * NV + v;
        const float4 nv = *(const float4*)(nodes + nb * (size_t)D + j0);
        store_bf4(Ash, KN2, row,   0 + j0, make_float4(ax, ay, az, aw));
        store_bf4(Ash, KN2, row, 128 + j0, nv);
    }
    __syncthreads();

    short8 wregB[4][2];
    #pragma unroll
    for (int ks = 0; ks < 4; ++ks)
        #pragma unroll
        for (int nt = 0; nt < 2; ++nt)
            wregB[ks][nt] = *(const short8*)(WtN + (size_t)(wv * 32 + nt * 16 + lc) * KN2
                                                 + (ks + 4) * 32 + lg * 8);

    f32x4 acc[4][2] = {};
    #pragma unroll
    for (int ks = 0; ks < 4; ++ks) {
        const int kk = ks * 32 + lg * 8;
        #pragma unroll
        for (int mt = 0; mt < 4; ++mt) {
            const int row  = mt * 16 + lc;
            const int byte = (kk * 2) ^ ((row & 7) << 4);
            const short8 afr = *(const short8*)(Ash + row * KN2 + (byte >> 1));
            acc[mt][0] = __builtin_amdgcn_mfma_f32_16x16x32_bf16(wregA[ks][0], afr, acc[mt][0], 0, 0, 0);
            acc[mt][1] = __builtin_amdgcn_mfma_f32_16x16x32_bf16(wregA[ks][1], afr, acc[mt][1], 0, 0, 0);
        }
    }
    #pragma unroll
    for (int ks = 0; ks < 4; ++ks) {
        const int kk = (ks + 4) * 32 + lg * 8;
        #pragma unroll
        for (int mt = 0; mt < 4; ++mt) {
            const int row  = mt * 16 + lc;
            const int byte = (kk * 2) ^ ((row & 7) << 4);
            const short8 afr = *(const short8*)(Ash + row * KN2 + (byte >> 1));
            acc[mt][0] = __builtin_amdgcn_mfma_f32_16x16x32_bf16(wregB[ks][0], afr, acc[mt][0], 0, 0, 0);
            acc[mt][1] = __builtin_amdgcn_mfma_f32_16x16x32_bf16(wregB[ks][1], afr, acc[mt][1], 0, 0, 0);
        }
    }

    #pragma unroll
    for (int nt = 0; nt < 2; ++nt) {
        const int f0 = wv * 32 + nt * 16 + lg * 4;
        const float4 bb = *(const float4*)(bias_n + (size_t)b * D + f0);
        float px = 0.f, py = 0.f, pz = 0.f, pw = 0.f;
        #pragma unroll
        for (int mt = 0; mt < 4; ++mt) {
            const int row = mt * 16 + lc;
            float4 o;
            o.x = fmaxf(acc[mt][nt][0] + bb.x, 0.f);
            o.y = fmaxf(acc[mt][nt][1] + bb.y, 0.f);
            o.z = fmaxf(acc[mt][nt][2] + bb.z, 0.f);
            o.w = fmaxf(acc[mt][nt][3] + bb.w, 0.f);
            *(float4*)(nodes_p + ((size_t)b * NV + n0 + row) * D + f0) = o;
            px += o.x; py += o.y; pz += o.z; pw += o.w;
        }
        #pragma unroll
        for (int m = 1; m < 16; m <<= 1) {
            px += __shfl_xor(px, m);
            py += __shfl_xor(py, m);
            pz += __shfl_xor(pz, m);
            pw += __shfl_xor(pw, m);
        }
        if (lc == 0) {
            float* dst = v2u + (size_t)b * D + f0;
            atomicAdd(dst + 0, px);
            atomicAdd(dst + 1, py);
            atomicAdd(dst + 2, pz);
            atomicAdd(dst + 3, pw);
        }
    }
}

// ---------------------------------------------------------------------------
// Global block: relu(concat(e2u, v2u, u) @ W_g + b_g)  (fp32, tiny)
// ---------------------------------------------------------------------------
__global__ __launch_bounds__(128) void glob_kernel(
    const float* __restrict__ e2u,
    const float* __restrict__ v2u,
    const float* __restrict__ gu,
    const float* __restrict__ W_glob,
    const float* __restrict__ b_glob,
    float* __restrict__ glob_p)
{
    __shared__ float gin[KG];
    const int b = blockIdx.x;
    const int j = threadIdx.x;

    gin[j      ] = e2u[(size_t)b * D + j];
    gin[j + 128] = v2u[(size_t)b * D + j];
    gin[j + 256] = gu [(size_t)b * D + j];
    __syncthreads();

    float acc = b_glob[j];
    #pragma unroll 4
    for (int k = 0; k < KG; ++k)
        acc += gin[k] * W_glob[(size_t)k * D + j];
    glob_p[(size_t)b * D + j] = fmaxf(acc, 0.f);
}

// ---------------------------------------------------------------------------
extern "C" void kernel_launch(void* const* d_in, const int* in_sizes, int n_in,
                              void* d_out, int out_size, void* d_ws, size_t ws_size,
                              hipStream_t stream) {
    const float* nodes      = (const float*)d_in[0];
    const float* edges      = (const float*)d_in[1];
    const float* gu         = (const float*)d_in[2];
    const int*   edge_rs    = (const int*)d_in[3];
    const int*   edge_masks = (const int*)d_in[4];
    const float* W_edge     = (const float*)d_in[5];
    const float* b_edge     = (const float*)d_in[6];
    const float* W_node     = (const float*)d_in[7];
    const float* b_node     = (const float*)d_in[8];
    const float* W_glob     = (const float*)d_in[9];
    const float* b_glob     = (const float*)d_in[10];

    float* out     = (float*)d_out;
    float* nodes_p = out;
    float* edges_p = out + (size_t)B * NV * D;
    float* glob_p  = edges_p + (size_t)B * NE * D;

    // workspace layout
    int*   cnt    = (int*)d_ws;                        // B*NV
    int*   off    = cnt + (size_t)B * NV;              // B*(NV+1)
    int*   cur    = off + (size_t)B * (NV + 1);        // B*NV
    int*   elist  = cur + (size_t)B * NV;              // B*NE
    float* e2u    = (float*)(elist + (size_t)B * NE);  // B*D
    float* v2u    = e2u + (size_t)B * D;               // B*D
    float* bias_e = v2u + (size_t)B * D;               // B*D
    float* bias_n = bias_e + (size_t)B * D;            // B*D
    unsigned short* WtE = (unsigned short*)(bias_n + (size_t)B * D);  // 128*384
    unsigned short* WtN = WtE + 128 * KE2;                            // 128*256

    hipMemsetAsync(cnt, 0, (size_t)B * NV * sizeof(int), stream);
    hipMemsetAsync(e2u, 0, 2 * (size_t)B * D * sizeof(float), stream);

    prep_weights<<<(128 * KE2) / 256, 256, 0, stream>>>(W_edge, W_node, WtE, WtN);
    bias_kernel<<<B, 128, 0, stream>>>(gu, W_edge, b_edge, W_node, b_node, bias_e, bias_n);
    hist_kernel<<<(B * NE) / 256, 256, 0, stream>>>(edge_rs, edge_masks, cnt);
    scan_kernel<<<B, 1024, 0, stream>>>(cnt, off, cur);
    scatter_kernel<<<(B * NE) / 256, 256, 0, stream>>>(edge_rs, edge_masks, cur, elist);

    dim3 eg(NE / 64, B);
    edge_kernel<<<eg, 256, 0, stream>>>(nodes, edges, edge_rs,
                                        WtE, bias_e, edges_p, e2u);
    dim3 ng(NV / 64, B);
    node_kernel<<<ng, 256, 0, stream>>>(nodes, edges_p, off, elist,
                                        WtN, bias_n, nodes_p, v2u);
    glob_kernel<<<B, 128, 0, stream>>>(e2u, v2u, gu, W_glob, b_glob, glob_p);
}